// Round 1
// baseline (998.246 us; speedup 1.0000x reference)
//
#include <hip/hip_runtime.h>
#include <hip/hip_bf16.h>

// GroupedEmbeddingBag: T=8 tables, N=200000 rows, D=128, B=8192 bags/table,
// L=163840 indices/table. out[b, t*D + d] = sum over bag of weights[t, idx, d].
// Memory-bound ragged gather-sum: ~671 MB gathered + 34 MB out.
//
// Mapping: one 64-lane wave per (t, b) bag. Lane l accumulates float2 at
// d = 2*l (64 lanes x 8 B = 512 B = one full row per load instruction).
// Unroll-by-4 over bag indices to keep 4 row loads in flight per wave.

#define EB_T 8
#define EB_N 200000
#define EB_D 128
#define EB_B 8192
#define EB_L 163840

__global__ __launch_bounds__(256) void GroupedEmbeddingBag_49864570306747_kernel(
    const float* __restrict__ weights,   // [T, N, D]
    const int*   __restrict__ values,    // [T, L]
    const int*   __restrict__ offsets,   // [T, B+1]
    float*       __restrict__ out)       // [B, T*D]
{
    const int wave_in_block = threadIdx.x >> 6;
    const int lane          = threadIdx.x & 63;
    const int w = (blockIdx.x << 2) + wave_in_block;   // global bag id in [0, T*B)
    const int t = w >> 13;          // w / B   (B = 8192)
    const int b = w & (EB_B - 1);   // w % B

    const int* __restrict__ offs = offsets + t * (EB_B + 1);
    const int start = offs[b];
    const int end   = offs[b + 1];

    const int* __restrict__ vals = values + (size_t)t * EB_L;
    // Row = 64 float2; lane covers float2 #lane of each gathered row.
    const float2* __restrict__ Wt =
        (const float2*)(weights + (size_t)t * EB_N * EB_D);

    float accx = 0.f, accy = 0.f;

    int i = start;
    for (; i + 4 <= end; i += 4) {
        const int r0 = vals[i + 0];
        const int r1 = vals[i + 1];
        const int r2 = vals[i + 2];
        const int r3 = vals[i + 3];
        const float2 v0 = Wt[(size_t)r0 * 64 + lane];
        const float2 v1 = Wt[(size_t)r1 * 64 + lane];
        const float2 v2 = Wt[(size_t)r2 * 64 + lane];
        const float2 v3 = Wt[(size_t)r3 * 64 + lane];
        accx += v0.x + v1.x + v2.x + v3.x;
        accy += v0.y + v1.y + v2.y + v3.y;
    }
    for (; i < end; ++i) {
        const int r = vals[i];
        const float2 v = Wt[(size_t)r * 64 + lane];
        accx += v.x;
        accy += v.y;
    }

    // out[b, t*D + 2*lane .. +1]
    float2* __restrict__ o =
        (float2*)(out + (size_t)b * (EB_T * EB_D) + t * EB_D);
    o[lane] = make_float2(accx, accy);
}

extern "C" void kernel_launch(void* const* d_in, const int* in_sizes, int n_in,
                              void* d_out, int out_size, void* d_ws, size_t ws_size,
                              hipStream_t stream) {
    const float* weights = (const float*)d_in[0];
    const int*   values  = (const int*)d_in[1];
    const int*   offsets = (const int*)d_in[2];
    float*       out     = (float*)d_out;

    // One wave per bag; 4 waves (bags) per 256-thread block.
    const int total_bags = EB_T * EB_B;          // 65536
    const int blocks     = total_bags / 4;       // 16384

    GroupedEmbeddingBag_49864570306747_kernel<<<blocks, 256, 0, stream>>>(
        weights, values, offsets, out);
}